// Round 3
// baseline (846.818 us; speedup 1.0000x reference)
//
#include <hip/hip_runtime.h>
#include <hip/hip_bf16.h>

#define NN 50000
#define NE 800000
#define D 128
#define NL 5
#define NR 2048
#define NO 65
#define BR 64
#define NBLK ((NN + BR - 1) / BR)

typedef unsigned short ushort_t;
typedef __attribute__((ext_vector_type(8))) short bf16x8;
typedef __attribute__((ext_vector_type(4))) float f32x4;

__device__ inline float bflo(unsigned u) {
    return __builtin_bit_cast(float, u << 16);
}
__device__ inline float bfhi(unsigned u) {
    return __builtin_bit_cast(float, u & 0xFFFF0000u);
}
__device__ inline ushort_t f2bf(float f) {
    unsigned u = __builtin_bit_cast(unsigned, f);
    u = (u + 0x7FFF + ((u >> 16) & 1)) >> 16;   // RNE
    return (ushort_t)u;
}
__device__ inline unsigned pk2(float a, float b) {
    return (unsigned)f2bf(a) | ((unsigned)f2bf(b) << 16);
}
__device__ inline void acc8(float* a, uint4 v) {
    a[0] += bflo(v.x); a[1] += bfhi(v.x);
    a[2] += bflo(v.y); a[3] += bfhi(v.y);
    a[4] += bflo(v.z); a[5] += bfhi(v.z);
    a[6] += bflo(v.w); a[7] += bfhi(v.w);
}

// ---------------- init: h0 = keys_emb[x0] + vals_emb[x1] ----------------
__global__ void k_init(const int* __restrict__ x, const float* __restrict__ ke,
                       const float* __restrict__ ve, float* __restrict__ h32,
                       ushort_t* __restrict__ h16) {
    int i = blockIdx.x * blockDim.x + threadIdx.x;
    if (i >= NN * D) return;
    int node = i >> 7, f = i & 127;
    float v = ke[x[node * 2 + 0] * D + f] + ve[x[node * 2 + 1] * D + f];
    h32[i] = v;
    h16[i] = f2bf(v);
}

// ---------------- weight convert+transpose to bf16 ----------------
__global__ void k_w1t(const float* __restrict__ W1, ushort_t* __restrict__ W1t) {
    int i = blockIdx.x * blockDim.x + threadIdx.x;
    if (i >= NL * 256 * 128) return;
    int l = i / 32768, r = i % 32768;
    int n = r >> 7, k = r & 127;
    W1t[i] = f2bf(W1[l * 32768 + k * 256 + n]);
}
__global__ void k_w2t(const float* __restrict__ W2, ushort_t* __restrict__ W2t) {
    int i = blockIdx.x * blockDim.x + threadIdx.x;
    if (i >= NL * 128 * 256) return;
    int l = i / 32768, r = i % 32768;
    int n = r >> 8, k = r & 255;
    W2t[i] = f2bf(W2[l * 32768 + k * 128 + n]);
}

// ---------------- CSR build (counting sort by dst) ----------------
__global__ void k_hist(const int* __restrict__ ei, int* __restrict__ deg) {
    int e = blockIdx.x * blockDim.x + threadIdx.x;
    if (e >= NE) return;
    atomicAdd(&deg[ei[NE + e]], 1);
}

__global__ void k_scan1(const int* __restrict__ deg, int* __restrict__ incl,
                        int* __restrict__ bsums) {
    __shared__ int s[256];
    int t = threadIdx.x, i = blockIdx.x * 256 + t;
    int v = (i < NN) ? deg[i] : 0;
    s[t] = v; __syncthreads();
    for (int off = 1; off < 256; off <<= 1) {
        int u = (t >= off) ? s[t - off] : 0;
        __syncthreads();
        s[t] += u; __syncthreads();
    }
    if (i < NN) incl[i] = s[t];
    if (t == 255) bsums[blockIdx.x] = s[255];
}

__global__ void k_scan2(int* __restrict__ bsums, int nb) {
    __shared__ int s[256];
    int t = threadIdx.x;
    int v = (t < nb) ? bsums[t] : 0;
    s[t] = v; __syncthreads();
    for (int off = 1; off < 256; off <<= 1) {
        int u = (t >= off) ? s[t - off] : 0;
        __syncthreads();
        s[t] += u; __syncthreads();
    }
    if (t < nb) bsums[t] = s[t] - v;   // exclusive
}

__global__ void k_scan3(const int* __restrict__ deg, const int* __restrict__ incl,
                        const int* __restrict__ bsums, int* __restrict__ rs,
                        int* __restrict__ cur) {
    int i = blockIdx.x * blockDim.x + threadIdx.x;
    if (i >= NN) return;
    int ex = incl[i] - deg[i] + bsums[i >> 8];
    rs[i] = ex; cur[i] = ex;
    if (i == 0) rs[NN] = NE;
}

__global__ void k_fill(const int* __restrict__ ei, int* __restrict__ cur,
                       int* __restrict__ csrc) {
    int e = blockIdx.x * blockDim.x + threadIdx.x;
    if (e >= NE) return;
    int s = ei[e], d = ei[NE + e];
    int pos = atomicAdd(&cur[d], 1);
    csrc[pos] = s;
}

// ============ fused layer: gather + MFMA MLP + residual + LN ============
// 64 rows/block, 256 threads (4 waves). Reads h(in), writes h(out).
__global__ void __launch_bounds__(256) k_layer(
        const ushort_t* __restrict__ h16i, const float* __restrict__ h32i,
        ushort_t* __restrict__ h16o, float* __restrict__ h32o,
        const int* __restrict__ rs, const int* __restrict__ csrc,
        const float* __restrict__ epsArr, const int layer,
        const ushort_t* __restrict__ W1t, const float* __restrict__ b1,
        const ushort_t* __restrict__ W2t, const float* __restrict__ b2,
        const float* __restrict__ lng, const float* __restrict__ lnb) {
    __shared__ ushort_t zs[BR * 128];   // 16 KB, XOR-swizzled (256 B rows)
    __shared__ ushort_t ts[BR * 256];   // 32 KB, XOR-swizzled (512 B rows)
    const int t = threadIdx.x;
    const int lane = t & 63, w = t >> 6;
    const int lr = lane & 15, lk = lane >> 4;
    const int row0 = blockIdx.x * BR;
    const float epsl = 1.f + epsArr[layer];
    const uint4* H4 = (const uint4*)h16i;

    // ---- gather: z = (1+eps)*h + sum_in h[src]; 4 edges in flight/wave ----
    for (int i = 0; i < 16; ++i) {
        const int r = w * 16 + i;
        const int node = row0 + r;
        float acc[8] = {0.f, 0.f, 0.f, 0.f, 0.f, 0.f, 0.f, 0.f};
        if (node < NN) {
            const int e0 = rs[node], e1 = rs[node + 1];
            const uint4 z4 = {0u, 0u, 0u, 0u};
            for (int eb = e0; eb < e1; eb += 16) {
                const int ea = eb + lk;              // group lk handles ea, ea+4, ea+8, ea+12
                uint4 v0 = (ea      < e1) ? H4[(size_t)csrc[ea     ] * 16 + lr] : z4;
                uint4 v1 = (ea + 4  < e1) ? H4[(size_t)csrc[ea + 4 ] * 16 + lr] : z4;
                uint4 v2 = (ea + 8  < e1) ? H4[(size_t)csrc[ea + 8 ] * 16 + lr] : z4;
                uint4 v3 = (ea + 12 < e1) ? H4[(size_t)csrc[ea + 12] * 16 + lr] : z4;
                acc8(acc, v0); acc8(acc, v1); acc8(acc, v2); acc8(acc, v3);
            }
            #pragma unroll
            for (int k = 0; k < 8; ++k) {
                acc[k] += __shfl_xor(acc[k], 16);
                acc[k] += __shfl_xor(acc[k], 32);
            }
            uint4 own = H4[(size_t)node * 16 + lr];
            acc[0] += epsl * bflo(own.x); acc[1] += epsl * bfhi(own.x);
            acc[2] += epsl * bflo(own.y); acc[3] += epsl * bfhi(own.y);
            acc[4] += epsl * bflo(own.z); acc[5] += epsl * bfhi(own.z);
            acc[6] += epsl * bflo(own.w); acc[7] += epsl * bfhi(own.w);
        }
        if (lk == 0) {
            uint4 o;
            o.x = pk2(acc[0], acc[1]); o.y = pk2(acc[2], acc[3]);
            o.z = pk2(acc[4], acc[5]); o.w = pk2(acc[6], acc[7]);
            const int byte = (r * 256 + lr * 16) ^ ((r & 7) << 4);
            *(uint4*)((char*)zs + byte) = o;
        }
    }
    __syncthreads();

    // ---- phase 1: C1^T = W1t(A) x z(B); wave w owns n-tiles 4w..4w+3 ----
    const ushort_t* W1p = W1t + (size_t)layer * 256 * 128;
    f32x4 acc1[4][4];   // [nt][rt]
    #pragma unroll
    for (int nt = 0; nt < 4; ++nt)
        #pragma unroll
        for (int rt = 0; rt < 4; ++rt) acc1[nt][rt] = (f32x4){0.f, 0.f, 0.f, 0.f};
    #pragma unroll
    for (int kk = 0; kk < 4; ++kk) {
        bf16x8 av[4], bv[4];
        #pragma unroll
        for (int nt = 0; nt < 4; ++nt)
            av[nt] = *(const bf16x8*)(W1p + (size_t)((w * 4 + nt) * 16 + lr) * 128 + kk * 32 + lk * 8);
        #pragma unroll
        for (int rt = 0; rt < 4; ++rt) {
            const int row = rt * 16 + lr;
            const int byte = (row * 256 + kk * 64 + lk * 16) ^ ((row & 7) << 4);
            bv[rt] = *(const bf16x8*)((const char*)zs + byte);
        }
        #pragma unroll
        for (int nt = 0; nt < 4; ++nt)
            #pragma unroll
            for (int rt = 0; rt < 4; ++rt)
                acc1[nt][rt] = __builtin_amdgcn_mfma_f32_16x16x32_bf16(av[nt], bv[rt], acc1[nt][rt], 0, 0, 0);
    }
    // bias + relu -> ts (lane holds 4 consecutive n-cols at one z-row)
    #pragma unroll
    for (int nt = 0; nt < 4; ++nt) {
        const int nc = (w * 4 + nt) * 16 + lk * 4;
        const float4 bb = *(const float4*)&b1[layer * 256 + nc];
        #pragma unroll
        for (int rt = 0; rt < 4; ++rt) {
            const int zrow = rt * 16 + lr;
            unsigned lo = pk2(fmaxf(acc1[nt][rt][0] + bb.x, 0.f),
                              fmaxf(acc1[nt][rt][1] + bb.y, 0.f));
            unsigned hi = pk2(fmaxf(acc1[nt][rt][2] + bb.z, 0.f),
                              fmaxf(acc1[nt][rt][3] + bb.w, 0.f));
            const int byte = (zrow * 512 + nc * 2) ^ ((zrow & 7) << 4);
            uint2 o; o.x = lo; o.y = hi;
            *(uint2*)((char*)ts + byte) = o;
        }
    }
    __syncthreads();

    // ---- phase 2: C2^T = W2t(A) x t(B); wave w owns row-tile w ----
    const ushort_t* W2p = W2t + (size_t)layer * 128 * 256;
    f32x4 acc2[8];
    #pragma unroll
    for (int nt = 0; nt < 8; ++nt) acc2[nt] = (f32x4){0.f, 0.f, 0.f, 0.f};
    const int myrow = w * 16 + lr;
    #pragma unroll
    for (int kk = 0; kk < 8; ++kk) {
        const int byte = (myrow * 512 + kk * 64 + lk * 16) ^ ((myrow & 7) << 4);
        const bf16x8 bv = *(const bf16x8*)((const char*)ts + byte);
        #pragma unroll
        for (int nt = 0; nt < 8; ++nt) {
            const bf16x8 av = *(const bf16x8*)(W2p + (size_t)(nt * 16 + lr) * 256 + kk * 32 + lk * 8);
            acc2[nt] = __builtin_amdgcn_mfma_f32_16x16x32_bf16(av, bv, acc2[nt], 0, 0, 0);
        }
    }

    // ---- bias + residual + LayerNorm (lane holds 32 cols of row `myrow`) ----
    const int grow = row0 + myrow;
    float vals[8][4];
    float s = 0.f, ss = 0.f;
    #pragma unroll
    for (int nt = 0; nt < 8; ++nt) {
        const int c = nt * 16 + lk * 4;
        const float4 bb = *(const float4*)&b2[layer * 128 + c];
        float4 hv = {0.f, 0.f, 0.f, 0.f};
        if (grow < NN) hv = *(const float4*)&h32i[(size_t)grow * 128 + c];
        float v0 = acc2[nt][0] + bb.x + hv.x;
        float v1 = acc2[nt][1] + bb.y + hv.y;
        float v2 = acc2[nt][2] + bb.z + hv.z;
        float v3 = acc2[nt][3] + bb.w + hv.w;
        vals[nt][0] = v0; vals[nt][1] = v1; vals[nt][2] = v2; vals[nt][3] = v3;
        s += v0 + v1 + v2 + v3;
        ss += v0 * v0 + v1 * v1 + v2 * v2 + v3 * v3;
    }
    s  += __shfl_xor(s, 16);  s  += __shfl_xor(s, 32);
    ss += __shfl_xor(ss, 16); ss += __shfl_xor(ss, 32);
    const float mu = s * (1.f / 128.f);
    const float rstd = rsqrtf(ss * (1.f / 128.f) - mu * mu + 1e-5f);
    if (grow < NN) {
        #pragma unroll
        for (int nt = 0; nt < 8; ++nt) {
            const int c = nt * 16 + lk * 4;
            const float4 g4 = *(const float4*)&lng[layer * 128 + c];
            const float4 b4 = *(const float4*)&lnb[layer * 128 + c];
            float4 o;
            o.x = (vals[nt][0] - mu) * rstd * g4.x + b4.x;
            o.y = (vals[nt][1] - mu) * rstd * g4.y + b4.y;
            o.z = (vals[nt][2] - mu) * rstd * g4.z + b4.z;
            o.w = (vals[nt][3] - mu) * rstd * g4.w + b4.w;
            *(float4*)&h32o[(size_t)grow * 128 + c] = o;
            uint2 p; p.x = pk2(o.x, o.y); p.y = pk2(o.z, o.w);
            *(uint2*)&h16o[(size_t)grow * 128 + c] = p;
        }
    }
}

// ---------------- readout: out = h[roots] @ W_out ----------------
__global__ void __launch_bounds__(256) k_out(const float* __restrict__ h,
                                             const int* __restrict__ roots,
                                             const float* __restrict__ Wo,
                                             float* __restrict__ out) {
    __shared__ float hs[16 * 128];
    int t = threadIdx.x;
    int r0 = blockIdx.x * 16;
    for (int i = t; i < 16 * 128; i += 256) {
        int rr = r0 + (i >> 7);
        hs[i] = h[(size_t)roots[rr] * 128 + (i & 127)];
    }
    __syncthreads();
    for (int o = t; o < 16 * NO; o += 256) {
        int j = o / NO, c = o % NO;
        float s = 0.f;
        for (int k = 0; k < 128; ++k) s += hs[j * 128 + k] * Wo[k * NO + c];
        out[(r0 + j) * NO + c] = s;
    }
}

extern "C" void kernel_launch(void* const* d_in, const int* in_sizes, int n_in,
                              void* d_out, int out_size, void* d_ws, size_t ws_size,
                              hipStream_t stream) {
    const int*   x    = (const int*)d_in[0];
    const int*   ei   = (const int*)d_in[1];
    const int*   roots= (const int*)d_in[2];
    const float* ke   = (const float*)d_in[3];
    const float* ve   = (const float*)d_in[4];
    const float* eps  = (const float*)d_in[5];
    const float* W1   = (const float*)d_in[6];
    const float* b1   = (const float*)d_in[7];
    const float* W2   = (const float*)d_in[8];
    const float* b2   = (const float*)d_in[9];
    const float* g    = (const float*)d_in[10];
    const float* bt   = (const float*)d_in[11];
    const float* Wo   = (const float*)d_in[12];
    float* out = (float*)d_out;

    char* ws = (char*)d_ws;
    size_t off = 0;
    auto alloc = [&](size_t bytes) {
        void* p = ws + off;
        off += (bytes + 255) & ~(size_t)255;
        return p;
    };
    float*    h32A = (float*)alloc((size_t)NN * D * 4);
    float*    h32B = (float*)alloc((size_t)NN * D * 4);
    ushort_t* h16A = (ushort_t*)alloc((size_t)NN * D * 2);
    ushort_t* h16B = (ushort_t*)alloc((size_t)NN * D * 2);
    ushort_t* W1tb = (ushort_t*)alloc((size_t)NL * 256 * 128 * 2);
    ushort_t* W2tb = (ushort_t*)alloc((size_t)NL * 128 * 256 * 2);
    int* deg  = (int*)alloc((size_t)NN * 4);
    int* incl = (int*)alloc((size_t)NN * 4);
    int* bsum = (int*)alloc(256 * 4);
    int* rs   = (int*)alloc((size_t)(NN + 1) * 4);
    int* cur  = (int*)alloc((size_t)NN * 4);
    int* csrc = (int*)alloc((size_t)NE * 4);

    hipMemsetAsync(deg, 0, (size_t)NN * 4, stream);

    k_init<<<(NN * D + 255) / 256, 256, 0, stream>>>(x, ke, ve, h32A, h16A);
    k_w1t<<<(NL * 32768 + 255) / 256, 256, 0, stream>>>(W1, W1tb);
    k_w2t<<<(NL * 32768 + 255) / 256, 256, 0, stream>>>(W2, W2tb);
    k_hist<<<(NE + 255) / 256, 256, 0, stream>>>(ei, deg);
    int nb = (NN + 255) / 256;
    k_scan1<<<nb, 256, 0, stream>>>(deg, incl, bsum);
    k_scan2<<<1, 256, 0, stream>>>(bsum, nb);
    k_scan3<<<nb, 256, 0, stream>>>(deg, incl, bsum, rs, cur);
    k_fill<<<(NE + 255) / 256, 256, 0, stream>>>(ei, cur, csrc);

    for (int l = 0; l < NL; ++l) {
        const ushort_t* hi16 = (l & 1) ? h16B : h16A;
        const float*    hi32 = (l & 1) ? h32B : h32A;
        ushort_t* ho16 = (l & 1) ? h16A : h16B;
        float*    ho32 = (l & 1) ? h32A : h32B;
        k_layer<<<NBLK, 256, 0, stream>>>(hi16, hi32, ho16, ho32, rs, csrc,
                                          eps, l, W1tb, b1, W2tb, b2, g, bt);
    }
    k_out<<<NR / 16, 256, 0, stream>>>(h32B, roots, Wo, out);
}

// Round 4
// 625.413 us; speedup vs baseline: 1.3540x; 1.3540x over previous
//
#include <hip/hip_runtime.h>
#include <hip/hip_bf16.h>

#define NN 50000
#define NE 800000
#define D 128
#define NL 5
#define NR 2048
#define NO 65
#define BR 64
#define NBLK ((NN + BR - 1) / BR)

typedef unsigned short ushort_t;
typedef __attribute__((ext_vector_type(8))) short bf16x8;
typedef __attribute__((ext_vector_type(4))) float f32x4;

__device__ inline float bflo(unsigned u) {
    return __builtin_bit_cast(float, u << 16);
}
__device__ inline float bfhi(unsigned u) {
    return __builtin_bit_cast(float, u & 0xFFFF0000u);
}
__device__ inline ushort_t f2bf(float f) {
    unsigned u = __builtin_bit_cast(unsigned, f);
    u = (u + 0x7FFF + ((u >> 16) & 1)) >> 16;   // RNE
    return (ushort_t)u;
}
__device__ inline unsigned pk2(float a, float b) {
    return (unsigned)f2bf(a) | ((unsigned)f2bf(b) << 16);
}
__device__ inline void acc8(float* a, uint4 v) {
    a[0] += bflo(v.x); a[1] += bfhi(v.x);
    a[2] += bflo(v.y); a[3] += bfhi(v.y);
    a[4] += bflo(v.z); a[5] += bfhi(v.z);
    a[6] += bflo(v.w); a[7] += bfhi(v.w);
}

// ---------------- init: h0 = keys_emb[x0] + vals_emb[x1] (bf16) --------------
__global__ void k_init(const int* __restrict__ x, const float* __restrict__ ke,
                       const float* __restrict__ ve, ushort_t* __restrict__ h16) {
    int i = blockIdx.x * blockDim.x + threadIdx.x;   // one per 4 features
    if (i >= NN * 32) return;
    int node = i >> 5, f4 = (i & 31) * 4;
    float4 a = *(const float4*)&ke[(size_t)x[node * 2 + 0] * D + f4];
    float4 b = *(const float4*)&ve[(size_t)x[node * 2 + 1] * D + f4];
    uint2 o;
    o.x = pk2(a.x + b.x, a.y + b.y);
    o.y = pk2(a.z + b.z, a.w + b.w);
    *(uint2*)&h16[(size_t)node * D + f4] = o;
}

// ---------------- weight convert+transpose to bf16 ----------------
__global__ void k_w1t(const float* __restrict__ W1, ushort_t* __restrict__ W1t) {
    int i = blockIdx.x * blockDim.x + threadIdx.x;
    if (i >= NL * 256 * 128) return;
    int l = i / 32768, r = i % 32768;
    int n = r >> 7, k = r & 127;
    W1t[i] = f2bf(W1[l * 32768 + k * 256 + n]);
}
__global__ void k_w2t(const float* __restrict__ W2, ushort_t* __restrict__ W2t) {
    int i = blockIdx.x * blockDim.x + threadIdx.x;
    if (i >= NL * 128 * 256) return;
    int l = i / 32768, r = i % 32768;
    int n = r >> 8, k = r & 255;
    W2t[i] = f2bf(W2[l * 32768 + k * 128 + n]);
}

// ---------------- CSR build (counting sort by dst) ----------------
__global__ void k_hist(const int* __restrict__ ei, int* __restrict__ deg) {
    int e = blockIdx.x * blockDim.x + threadIdx.x;
    if (e >= NE) return;
    atomicAdd(&deg[ei[NE + e]], 1);
}

__global__ void k_scan1(const int* __restrict__ deg, int* __restrict__ incl,
                        int* __restrict__ bsums) {
    __shared__ int s[256];
    int t = threadIdx.x, i = blockIdx.x * 256 + t;
    int v = (i < NN) ? deg[i] : 0;
    s[t] = v; __syncthreads();
    for (int off = 1; off < 256; off <<= 1) {
        int u = (t >= off) ? s[t - off] : 0;
        __syncthreads();
        s[t] += u; __syncthreads();
    }
    if (i < NN) incl[i] = s[t];
    if (t == 255) bsums[blockIdx.x] = s[255];
}

__global__ void k_scan2(int* __restrict__ bsums, int nb) {
    __shared__ int s[256];
    int t = threadIdx.x;
    int v = (t < nb) ? bsums[t] : 0;
    s[t] = v; __syncthreads();
    for (int off = 1; off < 256; off <<= 1) {
        int u = (t >= off) ? s[t - off] : 0;
        __syncthreads();
        s[t] += u; __syncthreads();
    }
    if (t < nb) bsums[t] = s[t] - v;   // exclusive
}

__global__ void k_scan3(const int* __restrict__ deg, const int* __restrict__ incl,
                        const int* __restrict__ bsums, int* __restrict__ rs,
                        int* __restrict__ cur) {
    int i = blockIdx.x * blockDim.x + threadIdx.x;
    if (i >= NN) return;
    int ex = incl[i] - deg[i] + bsums[i >> 8];
    rs[i] = ex; cur[i] = ex;
    if (i == 0) rs[NN] = NE;
}

__global__ void k_fill(const int* __restrict__ ei, int* __restrict__ cur,
                       int* __restrict__ csrc) {
    int e = blockIdx.x * blockDim.x + threadIdx.x;
    if (e >= NE) return;
    int s = ei[e], d = ei[NE + e];
    int pos = atomicAdd(&cur[d], 1);
    csrc[pos] = s;
}

// ------- aggregate: z16 = bf16((1+eps)*h + sum_in h[src]) -------
// one wave per node; 4 groups of 16 lanes, each group loads a full 256B row;
// 16 edges in flight per wave.
__global__ void __launch_bounds__(256) k_agg(const ushort_t* __restrict__ h16,
                                             const int* __restrict__ rs,
                                             const int* __restrict__ csrc,
                                             const float* __restrict__ epsArr, int layer,
                                             ushort_t* __restrict__ z16) {
    const int wv = (blockIdx.x * 256 + threadIdx.x) >> 6;
    if (wv >= NN) return;
    const int lane = threadIdx.x & 63;
    const int lr = lane & 15, lk = lane >> 4;
    const uint4* H4 = (const uint4*)h16;
    const int e0 = rs[wv], e1 = rs[wv + 1];
    const uint4 own = H4[(size_t)wv * 16 + lr];
    float acc[8] = {0.f, 0.f, 0.f, 0.f, 0.f, 0.f, 0.f, 0.f};
    const uint4 z4 = {0u, 0u, 0u, 0u};
    for (int eb = e0; eb < e1; eb += 16) {
        const int ea = eb + lk;
        uint4 v0 = (ea      < e1) ? H4[(size_t)csrc[ea     ] * 16 + lr] : z4;
        uint4 v1 = (ea + 4  < e1) ? H4[(size_t)csrc[ea + 4 ] * 16 + lr] : z4;
        uint4 v2 = (ea + 8  < e1) ? H4[(size_t)csrc[ea + 8 ] * 16 + lr] : z4;
        uint4 v3 = (ea + 12 < e1) ? H4[(size_t)csrc[ea + 12] * 16 + lr] : z4;
        acc8(acc, v0); acc8(acc, v1); acc8(acc, v2); acc8(acc, v3);
    }
    #pragma unroll
    for (int k = 0; k < 8; ++k) {
        acc[k] += __shfl_xor(acc[k], 16);
        acc[k] += __shfl_xor(acc[k], 32);
    }
    if (lk == 0) {
        const float epsl = 1.f + epsArr[layer];
        float r0 = acc[0] + epsl * bflo(own.x), r1 = acc[1] + epsl * bfhi(own.x);
        float r2 = acc[2] + epsl * bflo(own.y), r3 = acc[3] + epsl * bfhi(own.y);
        float r4 = acc[4] + epsl * bflo(own.z), r5 = acc[5] + epsl * bfhi(own.z);
        float r6 = acc[6] + epsl * bflo(own.w), r7 = acc[7] + epsl * bfhi(own.w);
        uint4 o;
        o.x = pk2(r0, r1); o.y = pk2(r2, r3);
        o.z = pk2(r4, r5); o.w = pk2(r6, r7);
        ((uint4*)z16)[(size_t)wv * 16 + lr] = o;
    }
}

// ---------------- MFMA MLP + residual + LayerNorm ----------------
// 64 rows/block, 4 waves. z from GLOBAL (no zs staging); t in swizzled LDS.
__global__ void __launch_bounds__(256) k_mlp(
        const ushort_t* __restrict__ z16,
        const ushort_t* __restrict__ h16i, ushort_t* __restrict__ h16o,
        const int layer,
        const ushort_t* __restrict__ W1t, const float* __restrict__ b1,
        const ushort_t* __restrict__ W2t, const float* __restrict__ b2,
        const float* __restrict__ lng, const float* __restrict__ lnb) {
    __shared__ ushort_t ts[BR * 256];   // 32 KB, XOR-swizzled (512 B rows)
    const int t = threadIdx.x;
    const int lane = t & 63, w = t >> 6;
    const int lr = lane & 15, lk = lane >> 4;
    const int row0 = blockIdx.x * BR;

    // ---- phase 1: C1^T = W1t(A) x z(B); wave w owns n-tiles 4w..4w+3 ----
    const ushort_t* W1p = W1t + (size_t)layer * 256 * 128;
    f32x4 acc1[4][4];   // [nt][rt]
    #pragma unroll
    for (int nt = 0; nt < 4; ++nt)
        #pragma unroll
        for (int rt = 0; rt < 4; ++rt) acc1[nt][rt] = (f32x4){0.f, 0.f, 0.f, 0.f};
    #pragma unroll
    for (int kk = 0; kk < 4; ++kk) {
        bf16x8 av[4], bv[4];
        #pragma unroll
        for (int nt = 0; nt < 4; ++nt)
            av[nt] = *(const bf16x8*)(W1p + (size_t)((w * 4 + nt) * 16 + lr) * 128 + kk * 32 + lk * 8);
        #pragma unroll
        for (int rt = 0; rt < 4; ++rt) {
            const int grow = row0 + rt * 16 + lr;
            bv[rt] = (grow < NN)
                ? *(const bf16x8*)(z16 + (size_t)grow * 128 + kk * 32 + lk * 8)
                : (bf16x8){0, 0, 0, 0, 0, 0, 0, 0};
        }
        #pragma unroll
        for (int nt = 0; nt < 4; ++nt)
            #pragma unroll
            for (int rt = 0; rt < 4; ++rt)
                acc1[nt][rt] = __builtin_amdgcn_mfma_f32_16x16x32_bf16(av[nt], bv[rt], acc1[nt][rt], 0, 0, 0);
    }
    // bias + relu -> ts (lane holds 4 consecutive n-cols at one z-row)
    #pragma unroll
    for (int nt = 0; nt < 4; ++nt) {
        const int nc = (w * 4 + nt) * 16 + lk * 4;
        const float4 bb = *(const float4*)&b1[layer * 256 + nc];
        #pragma unroll
        for (int rt = 0; rt < 4; ++rt) {
            const int zrow = rt * 16 + lr;
            unsigned lo = pk2(fmaxf(acc1[nt][rt][0] + bb.x, 0.f),
                              fmaxf(acc1[nt][rt][1] + bb.y, 0.f));
            unsigned hi = pk2(fmaxf(acc1[nt][rt][2] + bb.z, 0.f),
                              fmaxf(acc1[nt][rt][3] + bb.w, 0.f));
            const int byte = (zrow * 512 + nc * 2) ^ ((zrow & 7) << 4);
            uint2 o; o.x = lo; o.y = hi;
            *(uint2*)((char*)ts + byte) = o;
        }
    }
    __syncthreads();

    // ---- phase 2: C2^T = W2t(A) x t(B); wave w owns row-tile w ----
    const ushort_t* W2p = W2t + (size_t)layer * 128 * 256;
    f32x4 acc2[8];
    #pragma unroll
    for (int nt = 0; nt < 8; ++nt) acc2[nt] = (f32x4){0.f, 0.f, 0.f, 0.f};
    const int myrow = w * 16 + lr;
    #pragma unroll
    for (int kk = 0; kk < 8; ++kk) {
        const int byte = (myrow * 512 + kk * 64 + lk * 16) ^ ((myrow & 7) << 4);
        const bf16x8 bv = *(const bf16x8*)((const char*)ts + byte);
        #pragma unroll
        for (int nt = 0; nt < 8; ++nt) {
            const bf16x8 av = *(const bf16x8*)(W2p + (size_t)(nt * 16 + lr) * 256 + kk * 32 + lk * 8);
            acc2[nt] = __builtin_amdgcn_mfma_f32_16x16x32_bf16(av, bv, acc2[nt], 0, 0, 0);
        }
    }

    // ---- bias + residual(bf16) + LayerNorm (lane holds 32 cols of `myrow`) ----
    const int grow = row0 + myrow;
    float vals[8][4];
    float s = 0.f, ss = 0.f;
    #pragma unroll
    for (int nt = 0; nt < 8; ++nt) {
        const int c = nt * 16 + lk * 4;
        const float4 bb = *(const float4*)&b2[layer * 128 + c];
        float h0 = 0.f, h1 = 0.f, h2 = 0.f, h3 = 0.f;
        if (grow < NN) {
            uint2 hv = *(const uint2*)&h16i[(size_t)grow * 128 + c];
            h0 = bflo(hv.x); h1 = bfhi(hv.x);
            h2 = bflo(hv.y); h3 = bfhi(hv.y);
        }
        float v0 = acc2[nt][0] + bb.x + h0;
        float v1 = acc2[nt][1] + bb.y + h1;
        float v2 = acc2[nt][2] + bb.z + h2;
        float v3 = acc2[nt][3] + bb.w + h3;
        vals[nt][0] = v0; vals[nt][1] = v1; vals[nt][2] = v2; vals[nt][3] = v3;
        s += v0 + v1 + v2 + v3;
        ss += v0 * v0 + v1 * v1 + v2 * v2 + v3 * v3;
    }
    s  += __shfl_xor(s, 16);  s  += __shfl_xor(s, 32);
    ss += __shfl_xor(ss, 16); ss += __shfl_xor(ss, 32);
    const float mu = s * (1.f / 128.f);
    const float rstd = rsqrtf(ss * (1.f / 128.f) - mu * mu + 1e-5f);
    if (grow < NN) {
        #pragma unroll
        for (int nt = 0; nt < 8; ++nt) {
            const int c = nt * 16 + lk * 4;
            const float4 g4 = *(const float4*)&lng[layer * 128 + c];
            const float4 b4 = *(const float4*)&lnb[layer * 128 + c];
            float o0 = (vals[nt][0] - mu) * rstd * g4.x + b4.x;
            float o1 = (vals[nt][1] - mu) * rstd * g4.y + b4.y;
            float o2 = (vals[nt][2] - mu) * rstd * g4.z + b4.z;
            float o3 = (vals[nt][3] - mu) * rstd * g4.w + b4.w;
            uint2 p; p.x = pk2(o0, o1); p.y = pk2(o2, o3);
            *(uint2*)&h16o[(size_t)grow * 128 + c] = p;
        }
    }
}

// ---------------- readout: out = h[roots] @ W_out ----------------
__global__ void __launch_bounds__(256) k_out(const ushort_t* __restrict__ h,
                                             const int* __restrict__ roots,
                                             const float* __restrict__ Wo,
                                             float* __restrict__ out) {
    __shared__ float hs[16 * 128];
    int t = threadIdx.x;
    int r0 = blockIdx.x * 16;
    for (int i = t; i < 16 * 32; i += 256) {
        int row = i >> 5, u = i & 31;
        uint2 v = *(const uint2*)&h[(size_t)roots[r0 + row] * 128 + u * 4];
        hs[row * 128 + u * 4 + 0] = bflo(v.x);
        hs[row * 128 + u * 4 + 1] = bfhi(v.x);
        hs[row * 128 + u * 4 + 2] = bflo(v.y);
        hs[row * 128 + u * 4 + 3] = bfhi(v.y);
    }
    __syncthreads();
    for (int o = t; o < 16 * NO; o += 256) {
        int j = o / NO, c = o % NO;
        float s = 0.f;
        for (int k = 0; k < 128; ++k) s += hs[j * 128 + k] * Wo[k * NO + c];
        out[(r0 + j) * NO + c] = s;
    }
}

extern "C" void kernel_launch(void* const* d_in, const int* in_sizes, int n_in,
                              void* d_out, int out_size, void* d_ws, size_t ws_size,
                              hipStream_t stream) {
    const int*   x    = (const int*)d_in[0];
    const int*   ei   = (const int*)d_in[1];
    const int*   roots= (const int*)d_in[2];
    const float* ke   = (const float*)d_in[3];
    const float* ve   = (const float*)d_in[4];
    const float* eps  = (const float*)d_in[5];
    const float* W1   = (const float*)d_in[6];
    const float* b1   = (const float*)d_in[7];
    const float* W2   = (const float*)d_in[8];
    const float* b2   = (const float*)d_in[9];
    const float* g    = (const float*)d_in[10];
    const float* bt   = (const float*)d_in[11];
    const float* Wo   = (const float*)d_in[12];
    float* out = (float*)d_out;

    char* ws = (char*)d_ws;
    size_t off = 0;
    auto alloc = [&](size_t bytes) {
        void* p = ws + off;
        off += (bytes + 255) & ~(size_t)255;
        return p;
    };
    ushort_t* h16A = (ushort_t*)alloc((size_t)NN * D * 2);
    ushort_t* h16B = (ushort_t*)alloc((size_t)NN * D * 2);
    ushort_t* z16  = (ushort_t*)alloc((size_t)NN * D * 2);
    ushort_t* W1tb = (ushort_t*)alloc((size_t)NL * 256 * 128 * 2);
    ushort_t* W2tb = (ushort_t*)alloc((size_t)NL * 128 * 256 * 2);
    int* deg  = (int*)alloc((size_t)NN * 4);
    int* incl = (int*)alloc((size_t)NN * 4);
    int* bsum = (int*)alloc(256 * 4);
    int* rs   = (int*)alloc((size_t)(NN + 1) * 4);
    int* cur  = (int*)alloc((size_t)NN * 4);
    int* csrc = (int*)alloc((size_t)NE * 4);

    hipMemsetAsync(deg, 0, (size_t)NN * 4, stream);

    k_init<<<(NN * 32 + 255) / 256, 256, 0, stream>>>(x, ke, ve, h16A);
    k_w1t<<<(NL * 32768 + 255) / 256, 256, 0, stream>>>(W1, W1tb);
    k_w2t<<<(NL * 32768 + 255) / 256, 256, 0, stream>>>(W2, W2tb);
    k_hist<<<(NE + 255) / 256, 256, 0, stream>>>(ei, deg);
    int nb = (NN + 255) / 256;
    k_scan1<<<nb, 256, 0, stream>>>(deg, incl, bsum);
    k_scan2<<<1, 256, 0, stream>>>(bsum, nb);
    k_scan3<<<nb, 256, 0, stream>>>(deg, incl, bsum, rs, cur);
    k_fill<<<(NE + 255) / 256, 256, 0, stream>>>(ei, cur, csrc);

    for (int l = 0; l < NL; ++l) {
        const ushort_t* hi = (l & 1) ? h16B : h16A;
        ushort_t*       ho = (l & 1) ? h16A : h16B;
        k_agg<<<(NN * 64 + 255) / 256, 256, 0, stream>>>(hi, rs, csrc, eps, l, z16);
        k_mlp<<<NBLK, 256, 0, stream>>>(z16, hi, ho, l, W1tb, b1, W2tb, b2, g, bt);
    }
    k_out<<<NR / 16, 256, 0, stream>>>(h16B, roots, Wo, out);
}

// Round 5
// 591.673 us; speedup vs baseline: 1.4312x; 1.0570x over previous
//
#include <hip/hip_runtime.h>
#include <hip/hip_bf16.h>

#define NN 50000
#define NE 800000
#define D 128
#define NL 5
#define NR 2048
#define NO 65
#define BR 32
#define NBLK ((NN + BR - 1) / BR)

typedef unsigned short ushort_t;
typedef __attribute__((ext_vector_type(8))) short bf16x8;
typedef __attribute__((ext_vector_type(4))) float f32x4;

__device__ inline float bflo(unsigned u) {
    return __builtin_bit_cast(float, u << 16);
}
__device__ inline float bfhi(unsigned u) {
    return __builtin_bit_cast(float, u & 0xFFFF0000u);
}
__device__ inline ushort_t f2bf(float f) {
    unsigned u = __builtin_bit_cast(unsigned, f);
    u = (u + 0x7FFF + ((u >> 16) & 1)) >> 16;   // RNE
    return (ushort_t)u;
}
__device__ inline unsigned pk2(float a, float b) {
    return (unsigned)f2bf(a) | ((unsigned)f2bf(b) << 16);
}
__device__ inline void acc8(float* a, uint4 v) {
    a[0] += bflo(v.x); a[1] += bfhi(v.x);
    a[2] += bflo(v.y); a[3] += bfhi(v.y);
    a[4] += bflo(v.z); a[5] += bfhi(v.z);
    a[6] += bflo(v.w); a[7] += bfhi(v.w);
}

// ---------------- init: h0 = keys_emb[x0] + vals_emb[x1] (bf16) --------------
__global__ void k_init(const int* __restrict__ x, const float* __restrict__ ke,
                       const float* __restrict__ ve, ushort_t* __restrict__ h16) {
    int i = blockIdx.x * blockDim.x + threadIdx.x;   // one per 4 features
    if (i >= NN * 32) return;
    int node = i >> 5, f4 = (i & 31) * 4;
    float4 a = *(const float4*)&ke[(size_t)x[node * 2 + 0] * D + f4];
    float4 b = *(const float4*)&ve[(size_t)x[node * 2 + 1] * D + f4];
    uint2 o;
    o.x = pk2(a.x + b.x, a.y + b.y);
    o.y = pk2(a.z + b.z, a.w + b.w);
    *(uint2*)&h16[(size_t)node * D + f4] = o;
}

// ---------------- weight convert+transpose to bf16 ----------------
__global__ void k_w1t(const float* __restrict__ W1, ushort_t* __restrict__ W1t) {
    int i = blockIdx.x * blockDim.x + threadIdx.x;
    if (i >= NL * 256 * 128) return;
    int l = i / 32768, r = i % 32768;
    int n = r >> 7, k = r & 127;
    W1t[i] = f2bf(W1[l * 32768 + k * 256 + n]);
}
__global__ void k_w2t(const float* __restrict__ W2, ushort_t* __restrict__ W2t) {
    int i = blockIdx.x * blockDim.x + threadIdx.x;
    if (i >= NL * 128 * 256) return;
    int l = i / 32768, r = i % 32768;
    int n = r >> 8, k = r & 255;
    W2t[i] = f2bf(W2[l * 32768 + k * 128 + n]);
}

// ---------------- CSR build (counting sort by dst) ----------------
__global__ void k_hist(const int* __restrict__ ei, int* __restrict__ deg) {
    int e = blockIdx.x * blockDim.x + threadIdx.x;
    if (e >= NE) return;
    atomicAdd(&deg[ei[NE + e]], 1);
}

__global__ void k_scan1(const int* __restrict__ deg, int* __restrict__ incl,
                        int* __restrict__ bsums) {
    __shared__ int s[256];
    int t = threadIdx.x, i = blockIdx.x * 256 + t;
    int v = (i < NN) ? deg[i] : 0;
    s[t] = v; __syncthreads();
    for (int off = 1; off < 256; off <<= 1) {
        int u = (t >= off) ? s[t - off] : 0;
        __syncthreads();
        s[t] += u; __syncthreads();
    }
    if (i < NN) incl[i] = s[t];
    if (t == 255) bsums[blockIdx.x] = s[255];
}

__global__ void k_scan2(int* __restrict__ bsums, int nb) {
    __shared__ int s[256];
    int t = threadIdx.x;
    int v = (t < nb) ? bsums[t] : 0;
    s[t] = v; __syncthreads();
    for (int off = 1; off < 256; off <<= 1) {
        int u = (t >= off) ? s[t - off] : 0;
        __syncthreads();
        s[t] += u; __syncthreads();
    }
    if (t < nb) bsums[t] = s[t] - v;   // exclusive
}

__global__ void k_scan3(const int* __restrict__ deg, const int* __restrict__ incl,
                        const int* __restrict__ bsums, int* __restrict__ rs,
                        int* __restrict__ cur) {
    int i = blockIdx.x * blockDim.x + threadIdx.x;
    if (i >= NN) return;
    int ex = incl[i] - deg[i] + bsums[i >> 8];
    rs[i] = ex; cur[i] = ex;
    if (i == 0) rs[NN] = NE;
}

__global__ void k_fill(const int* __restrict__ ei, int* __restrict__ cur,
                       int* __restrict__ csrc) {
    int e = blockIdx.x * blockDim.x + threadIdx.x;
    if (e >= NE) return;
    int s = ei[e], d = ei[NE + e];
    int pos = atomicAdd(&cur[d], 1);
    csrc[pos] = s;
}

// ------- aggregate: z16 = bf16((1+eps)*h + sum_in h[src]) -------
// one wave per node; 4 groups of 16 lanes, each group loads a full 256B row;
// 16 edges in flight per wave.
__global__ void __launch_bounds__(256) k_agg(const ushort_t* __restrict__ h16,
                                             const int* __restrict__ rs,
                                             const int* __restrict__ csrc,
                                             const float* __restrict__ epsArr, int layer,
                                             ushort_t* __restrict__ z16) {
    const int wv = (blockIdx.x * 256 + threadIdx.x) >> 6;
    if (wv >= NN) return;
    const int lane = threadIdx.x & 63;
    const int lr = lane & 15, lk = lane >> 4;
    const uint4* H4 = (const uint4*)h16;
    const int e0 = rs[wv], e1 = rs[wv + 1];
    const uint4 own = H4[(size_t)wv * 16 + lr];
    float acc[8] = {0.f, 0.f, 0.f, 0.f, 0.f, 0.f, 0.f, 0.f};
    const uint4 z4 = {0u, 0u, 0u, 0u};
    for (int eb = e0; eb < e1; eb += 16) {
        const int ea = eb + lk;
        uint4 v0 = (ea      < e1) ? H4[(size_t)csrc[ea     ] * 16 + lr] : z4;
        uint4 v1 = (ea + 4  < e1) ? H4[(size_t)csrc[ea + 4 ] * 16 + lr] : z4;
        uint4 v2 = (ea + 8  < e1) ? H4[(size_t)csrc[ea + 8 ] * 16 + lr] : z4;
        uint4 v3 = (ea + 12 < e1) ? H4[(size_t)csrc[ea + 12] * 16 + lr] : z4;
        acc8(acc, v0); acc8(acc, v1); acc8(acc, v2); acc8(acc, v3);
    }
    #pragma unroll
    for (int k = 0; k < 8; ++k) {
        acc[k] += __shfl_xor(acc[k], 16);
        acc[k] += __shfl_xor(acc[k], 32);
    }
    if (lk == 0) {
        const float epsl = 1.f + epsArr[layer];
        float r0 = acc[0] + epsl * bflo(own.x), r1 = acc[1] + epsl * bfhi(own.x);
        float r2 = acc[2] + epsl * bflo(own.y), r3 = acc[3] + epsl * bfhi(own.y);
        float r4 = acc[4] + epsl * bflo(own.z), r5 = acc[5] + epsl * bfhi(own.z);
        float r6 = acc[6] + epsl * bflo(own.w), r7 = acc[7] + epsl * bfhi(own.w);
        uint4 o;
        o.x = pk2(r0, r1); o.y = pk2(r2, r3);
        o.z = pk2(r4, r5); o.w = pk2(r6, r7);
        ((uint4*)z16)[(size_t)wv * 16 + lr] = o;
    }
}

// ---------------- MFMA MLP + residual + LayerNorm ----------------
// 32 rows/block, 2 waves (128 thr). z and W from GLOBAL; t in swizzled LDS.
__global__ void __launch_bounds__(128) k_mlp(
        const ushort_t* __restrict__ z16,
        const ushort_t* __restrict__ h16i, ushort_t* __restrict__ h16o,
        const int layer,
        const ushort_t* __restrict__ W1t, const float* __restrict__ b1,
        const ushort_t* __restrict__ W2t, const float* __restrict__ b2,
        const float* __restrict__ lng, const float* __restrict__ lnb) {
    __shared__ ushort_t ts[BR * 256];   // 16 KB, XOR-swizzled (512 B rows)
    const int t = threadIdx.x;
    const int lane = t & 63, w = t >> 6;          // 2 waves
    const int lr = lane & 15, lk = lane >> 4;
    const int row0 = blockIdx.x * BR;

    // ---- prefetch residual rows (issue early, consume in epilogue) ----
    const int myrow = w * 16 + lr;
    const int grow = row0 + myrow;
    uint2 hres[8];
    #pragma unroll
    for (int nt = 0; nt < 8; ++nt) {
        hres[nt] = (uint2){0u, 0u};
        if (grow < NN)
            hres[nt] = *(const uint2*)&h16i[(size_t)grow * 128 + nt * 16 + lk * 4];
    }

    // ---- phase 1: C1^T = W1t(A) x z(B); wave w owns n-tiles 8w..8w+7 ----
    const ushort_t* W1p = W1t + (size_t)layer * 256 * 128;
    f32x4 acc1[8][2];   // [nt][rt]
    #pragma unroll
    for (int nt = 0; nt < 8; ++nt)
        #pragma unroll
        for (int rt = 0; rt < 2; ++rt) acc1[nt][rt] = (f32x4){0.f, 0.f, 0.f, 0.f};
    #pragma unroll
    for (int kk = 0; kk < 4; ++kk) {
        bf16x8 av[8], bv[2];
        #pragma unroll
        for (int nt = 0; nt < 8; ++nt)
            av[nt] = *(const bf16x8*)(W1p + (size_t)((w * 8 + nt) * 16 + lr) * 128 + kk * 32 + lk * 8);
        #pragma unroll
        for (int rt = 0; rt < 2; ++rt) {
            const int zrow = row0 + rt * 16 + lr;
            bv[rt] = (zrow < NN)
                ? *(const bf16x8*)(z16 + (size_t)zrow * 128 + kk * 32 + lk * 8)
                : (bf16x8){0, 0, 0, 0, 0, 0, 0, 0};
        }
        #pragma unroll
        for (int nt = 0; nt < 8; ++nt)
            #pragma unroll
            for (int rt = 0; rt < 2; ++rt)
                acc1[nt][rt] = __builtin_amdgcn_mfma_f32_16x16x32_bf16(av[nt], bv[rt], acc1[nt][rt], 0, 0, 0);
    }
    // bias + relu -> ts (lane holds 4 consecutive n-cols at one z-row)
    #pragma unroll
    for (int nt = 0; nt < 8; ++nt) {
        const int nc = (w * 8 + nt) * 16 + lk * 4;
        const float4 bb = *(const float4*)&b1[layer * 256 + nc];
        #pragma unroll
        for (int rt = 0; rt < 2; ++rt) {
            const int zrow = rt * 16 + lr;
            unsigned lo = pk2(fmaxf(acc1[nt][rt][0] + bb.x, 0.f),
                              fmaxf(acc1[nt][rt][1] + bb.y, 0.f));
            unsigned hi = pk2(fmaxf(acc1[nt][rt][2] + bb.z, 0.f),
                              fmaxf(acc1[nt][rt][3] + bb.w, 0.f));
            const int byte = (zrow * 512 + nc * 2) ^ ((zrow & 7) << 4);
            uint2 o; o.x = lo; o.y = hi;
            *(uint2*)((char*)ts + byte) = o;
        }
    }
    __syncthreads();

    // ---- phase 2: C2^T = W2t(A) x t(B); wave w owns row-tile w ----
    const ushort_t* W2p = W2t + (size_t)layer * 128 * 256;
    f32x4 acc2[8];
    #pragma unroll
    for (int nt = 0; nt < 8; ++nt) acc2[nt] = (f32x4){0.f, 0.f, 0.f, 0.f};
    #pragma unroll
    for (int kk = 0; kk < 8; ++kk) {
        const int byte = (myrow * 512 + kk * 64 + lk * 16) ^ ((myrow & 7) << 4);
        const bf16x8 bv = *(const bf16x8*)((const char*)ts + byte);
        #pragma unroll
        for (int nt = 0; nt < 8; ++nt) {
            const bf16x8 av = *(const bf16x8*)(W2p + (size_t)(nt * 16 + lr) * 256 + kk * 32 + lk * 8);
            acc2[nt] = __builtin_amdgcn_mfma_f32_16x16x32_bf16(av, bv, acc2[nt], 0, 0, 0);
        }
    }

    // ---- bias + residual(bf16) + LayerNorm (lane holds 32 cols of `myrow`) ----
    float vals[8][4];
    float s = 0.f, ss = 0.f;
    #pragma unroll
    for (int nt = 0; nt < 8; ++nt) {
        const int c = nt * 16 + lk * 4;
        const float4 bb = *(const float4*)&b2[layer * 128 + c];
        float v0 = acc2[nt][0] + bb.x + bflo(hres[nt].x);
        float v1 = acc2[nt][1] + bb.y + bfhi(hres[nt].x);
        float v2 = acc2[nt][2] + bb.z + bflo(hres[nt].y);
        float v3 = acc2[nt][3] + bb.w + bfhi(hres[nt].y);
        vals[nt][0] = v0; vals[nt][1] = v1; vals[nt][2] = v2; vals[nt][3] = v3;
        s += v0 + v1 + v2 + v3;
        ss += v0 * v0 + v1 * v1 + v2 * v2 + v3 * v3;
    }
    s  += __shfl_xor(s, 16);  s  += __shfl_xor(s, 32);
    ss += __shfl_xor(ss, 16); ss += __shfl_xor(ss, 32);
    const float mu = s * (1.f / 128.f);
    const float rstd = rsqrtf(ss * (1.f / 128.f) - mu * mu + 1e-5f);
    if (grow < NN) {
        #pragma unroll
        for (int nt = 0; nt < 8; ++nt) {
            const int c = nt * 16 + lk * 4;
            const float4 g4 = *(const float4*)&lng[layer * 128 + c];
            const float4 b4 = *(const float4*)&lnb[layer * 128 + c];
            float o0 = (vals[nt][0] - mu) * rstd * g4.x + b4.x;
            float o1 = (vals[nt][1] - mu) * rstd * g4.y + b4.y;
            float o2 = (vals[nt][2] - mu) * rstd * g4.z + b4.z;
            float o3 = (vals[nt][3] - mu) * rstd * g4.w + b4.w;
            uint2 p; p.x = pk2(o0, o1); p.y = pk2(o2, o3);
            *(uint2*)&h16o[(size_t)grow * 128 + c] = p;
        }
    }
}

// ---------------- readout: out = h[roots] @ W_out ----------------
__global__ void __launch_bounds__(256) k_out(const ushort_t* __restrict__ h,
                                             const int* __restrict__ roots,
                                             const float* __restrict__ Wo,
                                             float* __restrict__ out) {
    __shared__ float hs[16 * 128];
    int t = threadIdx.x;
    int r0 = blockIdx.x * 16;
    for (int i = t; i < 16 * 32; i += 256) {
        int row = i >> 5, u = i & 31;
        uint2 v = *(const uint2*)&h[(size_t)roots[r0 + row] * 128 + u * 4];
        hs[row * 128 + u * 4 + 0] = bflo(v.x);
        hs[row * 128 + u * 4 + 1] = bfhi(v.x);
        hs[row * 128 + u * 4 + 2] = bflo(v.y);
        hs[row * 128 + u * 4 + 3] = bfhi(v.y);
    }
    __syncthreads();
    for (int o = t; o < 16 * NO; o += 256) {
        int j = o / NO, c = o % NO;
        float s = 0.f;
        for (int k = 0; k < 128; ++k) s += hs[j * 128 + k] * Wo[k * NO + c];
        out[(r0 + j) * NO + c] = s;
    }
}

extern "C" void kernel_launch(void* const* d_in, const int* in_sizes, int n_in,
                              void* d_out, int out_size, void* d_ws, size_t ws_size,
                              hipStream_t stream) {
    const int*   x    = (const int*)d_in[0];
    const int*   ei   = (const int*)d_in[1];
    const int*   roots= (const int*)d_in[2];
    const float* ke   = (const float*)d_in[3];
    const float* ve   = (const float*)d_in[4];
    const float* eps  = (const float*)d_in[5];
    const float* W1   = (const float*)d_in[6];
    const float* b1   = (const float*)d_in[7];
    const float* W2   = (const float*)d_in[8];
    const float* b2   = (const float*)d_in[9];
    const float* g    = (const float*)d_in[10];
    const float* bt   = (const float*)d_in[11];
    const float* Wo   = (const float*)d_in[12];
    float* out = (float*)d_out;

    char* ws = (char*)d_ws;
    size_t off = 0;
    auto alloc = [&](size_t bytes) {
        void* p = ws + off;
        off += (bytes + 255) & ~(size_t)255;
        return p;
    };
    ushort_t* h16A = (ushort_t*)alloc((size_t)NN * D * 2);
    ushort_t* h16B = (ushort_t*)alloc((size_t)NN * D * 2);
    ushort_t* z16  = (ushort_t*)alloc((size_t)NN * D * 2);
    ushort_t* W1tb = (ushort_t*)alloc((size_t)NL * 256 * 128 * 2);
    ushort_t* W2tb = (ushort_t*)alloc((size_t)NL * 128 * 256 * 2);
    int* deg  = (int*)alloc((size_t)NN * 4);
    int* incl = (int*)alloc((size_t)NN * 4);
    int* bsum = (int*)alloc(256 * 4);
    int* rs   = (int*)alloc((size_t)(NN + 1) * 4);
    int* cur  = (int*)alloc((size_t)NN * 4);
    int* csrc = (int*)alloc((size_t)NE * 4);

    hipMemsetAsync(deg, 0, (size_t)NN * 4, stream);

    k_init<<<(NN * 32 + 255) / 256, 256, 0, stream>>>(x, ke, ve, h16A);
    k_w1t<<<(NL * 32768 + 255) / 256, 256, 0, stream>>>(W1, W1tb);
    k_w2t<<<(NL * 32768 + 255) / 256, 256, 0, stream>>>(W2, W2tb);
    k_hist<<<(NE + 255) / 256, 256, 0, stream>>>(ei, deg);
    int nb = (NN + 255) / 256;
    k_scan1<<<nb, 256, 0, stream>>>(deg, incl, bsum);
    k_scan2<<<1, 256, 0, stream>>>(bsum, nb);
    k_scan3<<<nb, 256, 0, stream>>>(deg, incl, bsum, rs, cur);
    k_fill<<<(NE + 255) / 256, 256, 0, stream>>>(ei, cur, csrc);

    for (int l = 0; l < NL; ++l) {
        const ushort_t* hi = (l & 1) ? h16B : h16A;
        ushort_t*       ho = (l & 1) ? h16A : h16B;
        k_agg<<<(NN * 64 + 255) / 256, 256, 0, stream>>>(hi, rs, csrc, eps, l, z16);
        k_mlp<<<NBLK, 128, 0, stream>>>(z16, hi, ho, l, W1tb, b1, W2tb, b2, g, bt);
    }
    k_out<<<NR / 16, 256, 0, stream>>>(h16B, roots, Wo, out);
}

// Round 6
// 493.223 us; speedup vs baseline: 1.7169x; 1.1996x over previous
//
#include <hip/hip_runtime.h>
#include <hip/hip_bf16.h>

#define NN 50000
#define NE 800000
#define D 128
#define NL 5
#define NR 2048
#define NO 65

typedef unsigned short ushort_t;
typedef __attribute__((ext_vector_type(8))) short bf16x8;
typedef __attribute__((ext_vector_type(4))) float f32x4;

__device__ inline float bflo(unsigned u) {
    return __builtin_bit_cast(float, u << 16);
}
__device__ inline float bfhi(unsigned u) {
    return __builtin_bit_cast(float, u & 0xFFFF0000u);
}
__device__ inline ushort_t f2bf(float f) {
    unsigned u = __builtin_bit_cast(unsigned, f);
    u = (u + 0x7FFF + ((u >> 16) & 1)) >> 16;   // RNE
    return (ushort_t)u;
}
__device__ inline unsigned pk2(float a, float b) {
    return (unsigned)f2bf(a) | ((unsigned)f2bf(b) << 16);
}
__device__ inline void acc8(float* a, uint4 v) {
    a[0] += bflo(v.x); a[1] += bfhi(v.x);
    a[2] += bflo(v.y); a[3] += bfhi(v.y);
    a[4] += bflo(v.z); a[5] += bfhi(v.z);
    a[6] += bflo(v.w); a[7] += bfhi(v.w);
}

// ---------------- init: h0 = keys_emb[x0] + vals_emb[x1] (bf16) --------------
__global__ void k_init(const int* __restrict__ x, const float* __restrict__ ke,
                       const float* __restrict__ ve, ushort_t* __restrict__ h16) {
    int i = blockIdx.x * blockDim.x + threadIdx.x;   // one per 4 features
    if (i >= NN * 32) return;
    int node = i >> 5, f4 = (i & 31) * 4;
    float4 a = *(const float4*)&ke[(size_t)x[node * 2 + 0] * D + f4];
    float4 b = *(const float4*)&ve[(size_t)x[node * 2 + 1] * D + f4];
    uint2 o;
    o.x = pk2(a.x + b.x, a.y + b.y);
    o.y = pk2(a.z + b.z, a.w + b.w);
    *(uint2*)&h16[(size_t)node * D + f4] = o;
}

// ---------------- weight convert+transpose to bf16 ----------------
__global__ void k_w1t(const float* __restrict__ W1, ushort_t* __restrict__ W1t) {
    int i = blockIdx.x * blockDim.x + threadIdx.x;
    if (i >= NL * 256 * 128) return;
    int l = i / 32768, r = i % 32768;
    int n = r >> 7, k = r & 127;
    W1t[i] = f2bf(W1[l * 32768 + k * 256 + n]);
}
__global__ void k_w2t(const float* __restrict__ W2, ushort_t* __restrict__ W2t) {
    int i = blockIdx.x * blockDim.x + threadIdx.x;
    if (i >= NL * 128 * 256) return;
    int l = i / 32768, r = i % 32768;
    int n = r >> 8, k = r & 255;
    W2t[i] = f2bf(W2[l * 32768 + k * 128 + n]);
}

// ---------------- CSR build (counting sort by dst) ----------------
__global__ void k_hist(const int* __restrict__ ei, int* __restrict__ deg) {
    int e = blockIdx.x * blockDim.x + threadIdx.x;
    if (e >= NE) return;
    atomicAdd(&deg[ei[NE + e]], 1);
}

__global__ void k_scan1(const int* __restrict__ deg, int* __restrict__ incl,
                        int* __restrict__ bsums) {
    __shared__ int s[256];
    int t = threadIdx.x, i = blockIdx.x * 256 + t;
    int v = (i < NN) ? deg[i] : 0;
    s[t] = v; __syncthreads();
    for (int off = 1; off < 256; off <<= 1) {
        int u = (t >= off) ? s[t - off] : 0;
        __syncthreads();
        s[t] += u; __syncthreads();
    }
    if (i < NN) incl[i] = s[t];
    if (t == 255) bsums[blockIdx.x] = s[255];
}

__global__ void k_scan2(int* __restrict__ bsums, int nb) {
    __shared__ int s[256];
    int t = threadIdx.x;
    int v = (t < nb) ? bsums[t] : 0;
    s[t] = v; __syncthreads();
    for (int off = 1; off < 256; off <<= 1) {
        int u = (t >= off) ? s[t - off] : 0;
        __syncthreads();
        s[t] += u; __syncthreads();
    }
    if (t < nb) bsums[t] = s[t] - v;   // exclusive
}

__global__ void k_scan3(const int* __restrict__ deg, const int* __restrict__ incl,
                        const int* __restrict__ bsums, int* __restrict__ rs,
                        int* __restrict__ cur) {
    int i = blockIdx.x * blockDim.x + threadIdx.x;
    if (i >= NN) return;
    int ex = incl[i] - deg[i] + bsums[i >> 8];
    rs[i] = ex; cur[i] = ex;
    if (i == 0) rs[NN] = NE;
}

__global__ void k_fill(const int* __restrict__ ei, int* __restrict__ cur,
                       int* __restrict__ csrc) {
    int e = blockIdx.x * blockDim.x + threadIdx.x;
    if (e >= NE) return;
    int s = ei[e], d = ei[NE + e];
    int pos = atomicAdd(&cur[d], 1);
    csrc[pos] = s;
}

// ------- aggregate: z16 = bf16((1+eps)*h + sum_in h[src]) -------
__global__ void __launch_bounds__(256) k_agg(const ushort_t* __restrict__ h16,
                                             const int* __restrict__ rs,
                                             const int* __restrict__ csrc,
                                             const float* __restrict__ epsArr, int layer,
                                             ushort_t* __restrict__ z16) {
    const int wv = (blockIdx.x * 256 + threadIdx.x) >> 6;
    if (wv >= NN) return;
    const int lane = threadIdx.x & 63;
    const int lr = lane & 15, lk = lane >> 4;
    const uint4* H4 = (const uint4*)h16;
    const int e0 = rs[wv], e1 = rs[wv + 1];
    const uint4 own = H4[(size_t)wv * 16 + lr];
    float acc[8] = {0.f, 0.f, 0.f, 0.f, 0.f, 0.f, 0.f, 0.f};
    const uint4 z4 = {0u, 0u, 0u, 0u};
    for (int eb = e0; eb < e1; eb += 16) {
        const int ea = eb + lk;
        uint4 v0 = (ea      < e1) ? H4[(size_t)csrc[ea     ] * 16 + lr] : z4;
        uint4 v1 = (ea + 4  < e1) ? H4[(size_t)csrc[ea + 4 ] * 16 + lr] : z4;
        uint4 v2 = (ea + 8  < e1) ? H4[(size_t)csrc[ea + 8 ] * 16 + lr] : z4;
        uint4 v3 = (ea + 12 < e1) ? H4[(size_t)csrc[ea + 12] * 16 + lr] : z4;
        acc8(acc, v0); acc8(acc, v1); acc8(acc, v2); acc8(acc, v3);
    }
    #pragma unroll
    for (int k = 0; k < 8; ++k) {
        acc[k] += __shfl_xor(acc[k], 16);
        acc[k] += __shfl_xor(acc[k], 32);
    }
    if (lk == 0) {
        const float epsl = 1.f + epsArr[layer];
        float r0 = acc[0] + epsl * bflo(own.x), r1 = acc[1] + epsl * bfhi(own.x);
        float r2 = acc[2] + epsl * bflo(own.y), r3 = acc[3] + epsl * bfhi(own.y);
        float r4 = acc[4] + epsl * bflo(own.z), r5 = acc[5] + epsl * bfhi(own.z);
        float r6 = acc[6] + epsl * bflo(own.w), r7 = acc[7] + epsl * bfhi(own.w);
        uint4 o;
        o.x = pk2(r0, r1); o.y = pk2(r2, r3);
        o.z = pk2(r4, r5); o.w = pk2(r6, r7);
        ((uint4*)z16)[(size_t)wv * 16 + lr] = o;
    }
}

// ============ persistent MFMA MLP + residual + LayerNorm ============
// 512 thr (8 waves), weights register-cached once, grid-stride over 32-row tiles.
// wave w: phase1 n-tiles {2w,2w+1}; phase2 row-tile rt=w&1, col-half ch=w>>1.
__global__ void __launch_bounds__(512, 2) k_mlp(
        const ushort_t* __restrict__ z16,
        const ushort_t* __restrict__ h16i, ushort_t* __restrict__ h16o,
        const int layer,
        const ushort_t* __restrict__ W1t, const float* __restrict__ b1,
        const ushort_t* __restrict__ W2t, const float* __restrict__ b2,
        const float* __restrict__ lng, const float* __restrict__ lnb) {
    __shared__ ushort_t ts[32 * 256];        // 16 KB, XOR-swizzled (512 B rows)
    __shared__ float red[2][16][4][2];       // cross-wave LN partials
    const int t = threadIdx.x;
    const int lane = t & 63, w = t >> 6;     // 8 waves
    const int lr = lane & 15, lk = lane >> 4;
    const int rt_w = w & 1, ch = w >> 1;

    // ---- register-cache weight fragments (once per block) ----
    const ushort_t* W1p = W1t + (size_t)layer * 256 * 128;
    const ushort_t* W2p = W2t + (size_t)layer * 128 * 256;
    bf16x8 fa1[2][4];
    #pragma unroll
    for (int nt = 0; nt < 2; ++nt)
        #pragma unroll
        for (int kk = 0; kk < 4; ++kk)
            fa1[nt][kk] = *(const bf16x8*)(W1p + (size_t)((w * 2 + nt) * 16 + lr) * 128 + kk * 32 + lk * 8);
    bf16x8 fa2[2][8];
    #pragma unroll
    for (int nt = 0; nt < 2; ++nt)
        #pragma unroll
        for (int kk = 0; kk < 8; ++kk)
            fa2[nt][kk] = *(const bf16x8*)(W2p + (size_t)((ch * 2 + nt) * 16 + lr) * 256 + kk * 32 + lk * 8);

    // per-lane bias/LN params (fixed columns)
    float4 bb1[2], bb2[2], g4[2], be4[2];
    #pragma unroll
    for (int nt = 0; nt < 2; ++nt) {
        bb1[nt] = *(const float4*)&b1[layer * 256 + (w * 2 + nt) * 16 + lk * 4];
        const int c = (ch * 2 + nt) * 16 + lk * 4;
        bb2[nt] = *(const float4*)&b2[layer * 128 + c];
        g4[nt]  = *(const float4*)&lng[layer * 128 + c];
        be4[nt] = *(const float4*)&lnb[layer * 128 + c];
    }

    const int NT = (NN + 31) / 32;
    const int myrow = rt_w * 16 + lr;
    for (int tile = blockIdx.x; tile < NT; tile += gridDim.x) {
        const int row0 = tile * 32;
        const int node = row0 + myrow;

        // residual prefetch (consumed in epilogue)
        uint2 hres[2] = {{0u, 0u}, {0u, 0u}};
        if (node < NN) {
            #pragma unroll
            for (int nt = 0; nt < 2; ++nt)
                hres[nt] = *(const uint2*)&h16i[(size_t)node * 128 + (ch * 2 + nt) * 16 + lk * 4];
        }

        // ---- phase 1: C1^T = W1(A) x z(B) ----
        f32x4 acc1[2][2];
        #pragma unroll
        for (int nt = 0; nt < 2; ++nt)
            #pragma unroll
            for (int rt = 0; rt < 2; ++rt) acc1[nt][rt] = (f32x4){0.f, 0.f, 0.f, 0.f};
        #pragma unroll
        for (int kk = 0; kk < 4; ++kk) {
            bf16x8 bv[2];
            #pragma unroll
            for (int rt = 0; rt < 2; ++rt) {
                const int zrow = row0 + rt * 16 + lr;
                bv[rt] = (zrow < NN)
                    ? *(const bf16x8*)(z16 + (size_t)zrow * 128 + kk * 32 + lk * 8)
                    : (bf16x8){0, 0, 0, 0, 0, 0, 0, 0};
            }
            #pragma unroll
            for (int nt = 0; nt < 2; ++nt)
                #pragma unroll
                for (int rt = 0; rt < 2; ++rt)
                    acc1[nt][rt] = __builtin_amdgcn_mfma_f32_16x16x32_bf16(fa1[nt][kk], bv[rt], acc1[nt][rt], 0, 0, 0);
        }
        // bias + relu -> ts (lane holds 4 consecutive n-cols at one z-row)
        #pragma unroll
        for (int nt = 0; nt < 2; ++nt) {
            const int nc = (w * 2 + nt) * 16 + lk * 4;
            #pragma unroll
            for (int rt = 0; rt < 2; ++rt) {
                const int zrow = rt * 16 + lr;
                unsigned lo = pk2(fmaxf(acc1[nt][rt][0] + bb1[nt].x, 0.f),
                                  fmaxf(acc1[nt][rt][1] + bb1[nt].y, 0.f));
                unsigned hi = pk2(fmaxf(acc1[nt][rt][2] + bb1[nt].z, 0.f),
                                  fmaxf(acc1[nt][rt][3] + bb1[nt].w, 0.f));
                const int byte = (zrow * 512 + nc * 2) ^ ((zrow & 7) << 4);
                uint2 o; o.x = lo; o.y = hi;
                *(uint2*)((char*)ts + byte) = o;
            }
        }
        __syncthreads();

        // ---- phase 2: C2^T = W2(A) x t(B); rows rt_w*16.., cols ch*32.. ----
        f32x4 acc2[2];
        acc2[0] = (f32x4){0.f, 0.f, 0.f, 0.f};
        acc2[1] = (f32x4){0.f, 0.f, 0.f, 0.f};
        #pragma unroll
        for (int kk = 0; kk < 8; ++kk) {
            const int byte = (myrow * 512 + kk * 64 + lk * 16) ^ ((myrow & 7) << 4);
            const bf16x8 bv = *(const bf16x8*)((const char*)ts + byte);
            acc2[0] = __builtin_amdgcn_mfma_f32_16x16x32_bf16(fa2[0][kk], bv, acc2[0], 0, 0, 0);
            acc2[1] = __builtin_amdgcn_mfma_f32_16x16x32_bf16(fa2[1][kk], bv, acc2[1], 0, 0, 0);
        }

        // ---- bias + residual + LN partials (lane: 8 cols of row `myrow`) ----
        float vals[2][4];
        float s = 0.f, ss = 0.f;
        #pragma unroll
        for (int nt = 0; nt < 2; ++nt) {
            float v0 = acc2[nt][0] + bb2[nt].x + bflo(hres[nt].x);
            float v1 = acc2[nt][1] + bb2[nt].y + bfhi(hres[nt].x);
            float v2 = acc2[nt][2] + bb2[nt].z + bflo(hres[nt].y);
            float v3 = acc2[nt][3] + bb2[nt].w + bfhi(hres[nt].y);
            vals[nt][0] = v0; vals[nt][1] = v1; vals[nt][2] = v2; vals[nt][3] = v3;
            s += v0 + v1 + v2 + v3;
            ss += v0 * v0 + v1 * v1 + v2 * v2 + v3 * v3;
        }
        s  += __shfl_xor(s, 16);  s  += __shfl_xor(s, 32);
        ss += __shfl_xor(ss, 16); ss += __shfl_xor(ss, 32);
        if (lk == 0) {
            red[rt_w][lr][ch][0] = s;
            red[rt_w][lr][ch][1] = ss;
        }
        __syncthreads();

        // cross-wave combine (4 col-halves per row)
        float st = red[rt_w][lr][0][0] + red[rt_w][lr][1][0] + red[rt_w][lr][2][0] + red[rt_w][lr][3][0];
        float sst = red[rt_w][lr][0][1] + red[rt_w][lr][1][1] + red[rt_w][lr][2][1] + red[rt_w][lr][3][1];
        const float mu = st * (1.f / 128.f);
        const float rstd = rsqrtf(sst * (1.f / 128.f) - mu * mu + 1e-5f);
        if (node < NN) {
            #pragma unroll
            for (int nt = 0; nt < 2; ++nt) {
                const int c = (ch * 2 + nt) * 16 + lk * 4;
                float o0 = (vals[nt][0] - mu) * rstd * g4[nt].x + be4[nt].x;
                float o1 = (vals[nt][1] - mu) * rstd * g4[nt].y + be4[nt].y;
                float o2 = (vals[nt][2] - mu) * rstd * g4[nt].z + be4[nt].z;
                float o3 = (vals[nt][3] - mu) * rstd * g4[nt].w + be4[nt].w;
                uint2 p; p.x = pk2(o0, o1); p.y = pk2(o2, o3);
                *(uint2*)&h16o[(size_t)node * 128 + c] = p;
            }
        }
    }
}

// ---------------- readout: out = h[roots] @ W_out ----------------
__global__ void __launch_bounds__(256) k_out(const ushort_t* __restrict__ h,
                                             const int* __restrict__ roots,
                                             const float* __restrict__ Wo,
                                             float* __restrict__ out) {
    __shared__ float hs[16 * 128];
    int t = threadIdx.x;
    int r0 = blockIdx.x * 16;
    for (int i = t; i < 16 * 32; i += 256) {
        int row = i >> 5, u = i & 31;
        uint2 v = *(const uint2*)&h[(size_t)roots[r0 + row] * 128 + u * 4];
        hs[row * 128 + u * 4 + 0] = bflo(v.x);
        hs[row * 128 + u * 4 + 1] = bfhi(v.x);
        hs[row * 128 + u * 4 + 2] = bflo(v.y);
        hs[row * 128 + u * 4 + 3] = bfhi(v.y);
    }
    __syncthreads();
    for (int o = t; o < 16 * NO; o += 256) {
        int j = o / NO, c = o % NO;
        float s = 0.f;
        for (int k = 0; k < 128; ++k) s += hs[j * 128 + k] * Wo[k * NO + c];
        out[(r0 + j) * NO + c] = s;
    }
}

extern "C" void kernel_launch(void* const* d_in, const int* in_sizes, int n_in,
                              void* d_out, int out_size, void* d_ws, size_t ws_size,
                              hipStream_t stream) {
    const int*   x    = (const int*)d_in[0];
    const int*   ei   = (const int*)d_in[1];
    const int*   roots= (const int*)d_in[2];
    const float* ke   = (const float*)d_in[3];
    const float* ve   = (const float*)d_in[4];
    const float* eps  = (const float*)d_in[5];
    const float* W1   = (const float*)d_in[6];
    const float* b1   = (const float*)d_in[7];
    const float* W2   = (const float*)d_in[8];
    const float* b2   = (const float*)d_in[9];
    const float* g    = (const float*)d_in[10];
    const float* bt   = (const float*)d_in[11];
    const float* Wo   = (const float*)d_in[12];
    float* out = (float*)d_out;

    char* ws = (char*)d_ws;
    size_t off = 0;
    auto alloc = [&](size_t bytes) {
        void* p = ws + off;
        off += (bytes + 255) & ~(size_t)255;
        return p;
    };
    ushort_t* h16A = (ushort_t*)alloc((size_t)NN * D * 2);
    ushort_t* h16B = (ushort_t*)alloc((size_t)NN * D * 2);
    ushort_t* z16  = (ushort_t*)alloc((size_t)NN * D * 2);
    ushort_t* W1tb = (ushort_t*)alloc((size_t)NL * 256 * 128 * 2);
    ushort_t* W2tb = (ushort_t*)alloc((size_t)NL * 128 * 256 * 2);
    int* deg  = (int*)alloc((size_t)NN * 4);
    int* incl = (int*)alloc((size_t)NN * 4);
    int* bsum = (int*)alloc(256 * 4);
    int* rs   = (int*)alloc((size_t)(NN + 1) * 4);
    int* cur  = (int*)alloc((size_t)NN * 4);
    int* csrc = (int*)alloc((size_t)NE * 4);

    hipMemsetAsync(deg, 0, (size_t)NN * 4, stream);

    k_init<<<(NN * 32 + 255) / 256, 256, 0, stream>>>(x, ke, ve, h16A);
    k_w1t<<<(NL * 32768 + 255) / 256, 256, 0, stream>>>(W1, W1tb);
    k_w2t<<<(NL * 32768 + 255) / 256, 256, 0, stream>>>(W2, W2tb);
    k_hist<<<(NE + 255) / 256, 256, 0, stream>>>(ei, deg);
    int nb = (NN + 255) / 256;
    k_scan1<<<nb, 256, 0, stream>>>(deg, incl, bsum);
    k_scan2<<<1, 256, 0, stream>>>(bsum, nb);
    k_scan3<<<nb, 256, 0, stream>>>(deg, incl, bsum, rs, cur);
    k_fill<<<(NE + 255) / 256, 256, 0, stream>>>(ei, cur, csrc);

    for (int l = 0; l < NL; ++l) {
        const ushort_t* hi = (l & 1) ? h16B : h16A;
        ushort_t*       ho = (l & 1) ? h16A : h16B;
        k_agg<<<(NN * 64 + 255) / 256, 256, 0, stream>>>(hi, rs, csrc, eps, l, z16);
        k_mlp<<<256, 512, 0, stream>>>(z16, hi, ho, l, W1tb, b1, W2tb, b2, g, bt);
    }
    k_out<<<NR / 16, 256, 0, stream>>>(h16B, roots, Wo, out);
}